// Round 10
// baseline (1431.220 us; speedup 1.0000x reference)
//
#include <hip/hip_runtime.h>
#include <cmath>

#define BB 16
#define NN 1024
#define KK1 205
#define KK2 42
#define CAP 96
#define GRID 512
#define TPB 256

struct MegaArgs {
  const float *x, *adj, *Wd0, *bd0, *Wd1, *bd1, *Wd2, *bd2;
  const float *Wu0, *bu0, *Wu1, *bu1, *p1, *p2, *gamma, *beta;
  const float *W1, *b1, *W2, *b2, *W3, *b3;
  float* out;
  int* bar;                // [0]=cnt, [1]=gen (memset to 0 pre-launch)
  float* dis0; int* ncnt; int* nbr; unsigned long long* mask;
  float* dxw; float* h0;
  int* perm1; float* vals1; int* inv1;
  float* A1; float* dis1; float* t1; float* h1;
  int* perm2; float* vals2; int* inv2;
  float* A2; float* dis2; float* t2; float* h2;
  float* hu0; float* hfin; float* pacc;
};

// ---- software grid barrier (monotonic generation, agent scope) ------------
__device__ __forceinline__ void gbar(int* bar, int& phase) {
  __syncthreads();
  if (threadIdx.x == 0) {
    int target = phase + 1;
    int arrived = __hip_atomic_fetch_add(&bar[0], 1, __ATOMIC_ACQ_REL,
                                         __HIP_MEMORY_SCOPE_AGENT);
    if (arrived == GRID - 1) {
      __hip_atomic_store(&bar[0], 0, __ATOMIC_RELAXED, __HIP_MEMORY_SCOPE_AGENT);
      __hip_atomic_store(&bar[1], target, __ATOMIC_RELEASE, __HIP_MEMORY_SCOPE_AGENT);
    } else {
      while (__hip_atomic_load(&bar[1], __ATOMIC_ACQUIRE,
                               __HIP_MEMORY_SCOPE_AGENT) < target)
        __builtin_amdgcn_s_sleep(2);
    }
  }
  __syncthreads();
  phase = phase + 1;
}

// ---- sparse GCN apply over binary adjacency (x4-unrolled gather) ----------
__device__ __forceinline__ void phase_spmm(const MegaArgs& a, const float* dxw,
                                           const float* bias, float* out,
                                           bool relu, int tid) {
  for (int vb = blockIdx.x; vb < BB * NN / 8; vb += GRID) {
    int g = tid >> 5, f = tid & 31;
    int node = vb * 8 + g;
    int b = node >> 10;
    int cnt = a.ncnt[node];
    const int* lst = a.nbr + (size_t)node * CAP;
    const float* dbase = dxw + ((size_t)(b << 10) << 5);
    float a0 = 0.f, a1 = 0.f, a2 = 0.f, a3 = 0.f;
    int k = 0;
    for (; k + 4 <= cnt; k += 4) {
      int4 j4 = *(const int4*)(lst + k);
      a0 += dbase[(size_t)j4.x * 32 + f];
      a1 += dbase[(size_t)j4.y * 32 + f];
      a2 += dbase[(size_t)j4.z * 32 + f];
      a3 += dbase[(size_t)j4.w * 32 + f];
    }
    for (; k < cnt; ++k) a0 += dbase[(size_t)lst[k] * 32 + f];
    float acc = (a0 + a1) + (a2 + a3);
    acc += 2.0f * dxw[(size_t)node * 32 + f];
    float r = a.dis0[node] * acc + bias[f];
    if (relu) r = fmaxf(r, 0.f);
    out[(size_t)node * 32 + f] = r;
  }
}

// ---- dense GCN apply, M compile-time, one row per vb ----------------------
template<int M>
__device__ __forceinline__ void phase_dense(const float* A, const float* t,
                                            const float* dis, const float* bias,
                                            float* out, int tid, float* ls) {
  for (int vb = blockIdx.x; vb < BB * M; vb += GRID) {
    __syncthreads();
    int row = vb, b = row / M, i = row - b * M;
    int g = tid >> 5, f = tid & 31;
    const float* Ar = A + (size_t)row * M;
    const float* tb = t + (size_t)b * M * 32;
    float acc = 0.f;
    for (int j = g; j < M; j += 8) acc += Ar[j] * tb[j * 32 + f];
    ls[g * 32 + f] = acc;
    __syncthreads();
    if (tid < 32) {
      float s = 0.f;
#pragma unroll
      for (int q = 0; q < 8; ++q) s += ls[q * 32 + tid];
      s += 2.0f * tb[i * 32 + tid];
      float r = dis[row] * s + bias[tid];
      out[(size_t)row * 32 + tid] = fmaxf(r, 0.f);
    }
  }
}

// ---- t = dis*vals*(h[perm]@W) ---------------------------------------------
__device__ __forceinline__ void phase_xw32g(const float* h, const int* perm,
                                            const float* vals, const float* W,
                                            const float* dis, int M, int K,
                                            int nvb, float* out, int tid) {
  for (int vb = blockIdx.x; vb < nvb; vb += GRID) {
    int idx = vb * TPB + tid;
    int f = idx & 31, q = idx >> 5;
    int b = q / K;
    int src = perm[q];
    const float* xr = h + (size_t)(b * M + src) * 32;
    float s = 0.f;
#pragma unroll
    for (int k = 0; k < 32; ++k) s += xr[k] * W[k * 32 + f];
    out[idx] = s * dis[q] * vals[q];
  }
}

// ---- t = dis*((h + unpool(up))@W) -----------------------------------------
__device__ __forceinline__ void phase_xw32u(const float* h, const float* up,
                                            const int* inv, const float* W,
                                            const float* dis, int M, int K,
                                            int nvb, float* out, int tid) {
  for (int vb = blockIdx.x; vb < nvb; vb += GRID) {
    int idx = vb * TPB + tid;
    int f = idx & 31, node = idx >> 5;
    int b = node / M;
    int iv = inv[node];
    const float* xr = h + (size_t)node * 32;
    float s = 0.f;
    if (iv >= 0) {
      const float* ur = up + (size_t)(b * K + iv) * 32;
#pragma unroll
      for (int k = 0; k < 32; ++k) s += (xr[k] + ur[k]) * W[k * 32 + f];
    } else {
#pragma unroll
      for (int k = 0; k < 32; ++k) s += xr[k] * W[k * 32 + f];
    }
    out[idx] = s * dis[node];
  }
}

__global__ __launch_bounds__(TPB, 2) void k_mega(MegaArgs a) {
  __shared__ __align__(16) unsigned char smem[27072];
  int tid = threadIdx.x;
  int phase = 0;

  // ---- P0: adj pass (float4): degree, interleaved bitmask, CSR, x@Wd0 ----
  for (int vb = blockIdx.x; vb < BB * NN / 4; vb += GRID) {
    int row = vb * 4 + (tid >> 6);
    int lane = tid & 63;
    const float4* ar = (const float4*)(a.adj + (size_t)row * NN);
    int base = 0;
    for (int c = 0; c < 4; ++c) {
      float4 v4 = ar[c * 64 + lane];
      float vv[4] = {v4.x, v4.y, v4.z, v4.w};
#pragma unroll
      for (int q = 0; q < 4; ++q) {
        unsigned long long m = __ballot(vv[q] != 0.0f);
        int w = c * 4 + q;
        if (lane == w) a.mask[(size_t)row * 16 + w] = m;
        if (vv[q] != 0.0f) {
          int pos = base + __popcll(m & ((1ull << lane) - 1ull));
          if (pos < CAP) a.nbr[(size_t)row * CAP + pos] = c * 256 + lane * 4 + q;
        }
        base += __popcll(m);
      }
    }
    float dis = rsqrtf((float)base + 2.0f);
    if (lane == 0) {
      a.ncnt[row] = base < CAP ? base : CAP;
      a.dis0[row] = dis;
    }
    if (lane < 32) {
      float x0 = a.x[row * 3], x1 = a.x[row * 3 + 1], x2 = a.x[row * 3 + 2];
      float s = x0 * a.Wd0[lane] + x1 * a.Wd0[32 + lane] + x2 * a.Wd0[64 + lane];
      a.dxw[(size_t)row * 32 + lane] = s * dis;
    }
  }
  gbar(a.bar, phase);

  // ---- P1: GCN0 apply (sparse, relu) -> h0 ----
  phase_spmm(a, a.dxw, a.bd0, a.h0, true, tid);
  gbar(a.bar, phase);

  // ---- P2: top-k pool 1 (rank selection; 16 batches x 4 chunks) ----
  for (int vb = blockIdx.x; vb < 64; vb += GRID) {
    int b = vb >> 2, chunk = vb & 3;
    float* ss = (float*)smem;                      // 1024 floats
    float nn = 0.f;
#pragma unroll
    for (int k = 0; k < 32; ++k) nn += a.p1[k] * a.p1[k];
    float rn = sqrtf(nn);
    for (int n = tid; n < NN; n += TPB) {
      const float* hr = a.h0 + (size_t)(b * NN + n) * 32;
      float d = 0.f;
#pragma unroll
      for (int k = 0; k < 32; ++k) d += hr[k] * a.p1[k];
      ss[n] = tanhf(d / rn);
    }
    __syncthreads();
    int c = chunk * 256 + tid;
    float v = ss[c];
    int rank = 0;
    for (int j = 0; j < NN; j += 8) {
#pragma unroll
      for (int q = 0; q < 8; ++q) {
        float sj = ss[j + q];
        rank += (sj > v || (sj == v && (j + q) < c)) ? 1 : 0;
      }
    }
    if (rank < KK1) {
      a.perm1[b * KK1 + rank] = c;
      a.vals1[b * KK1 + rank] = v;
      a.inv1[b * NN + c] = rank;
    } else {
      a.inv1[b * NN + c] = -1;
    }
  }
  gbar(a.bar, phase);

  // ---- P3a: A1 = augment(adj)[perm1,perm1] via bitsets (+dis1) ----
  for (int vb = blockIdx.x; vb < BB * 52; vb += GRID) {
    __syncthreads();
    int b = vb / 52, chunk = vb - b * 52;
    unsigned long long* smT = (unsigned long long*)smem;   // 16*KK1 u64
    int* sp = (int*)(smem + 26240);                        // KK1 ints
    if (tid < KK1) sp[tid] = a.perm1[b * KK1 + tid];
    __syncthreads();
    for (int q = tid; q < KK1 * 16; q += TPB) {
      int i = q >> 4, w = q & 15;
      smT[w * KK1 + i] = a.mask[((size_t)(b * NN + sp[i])) * 16 + w];
    }
    __syncthreads();
    int wave = tid >> 6, lane = tid & 63;
    int i = chunk * 4 + wave;
    if (i < KK1) {
      unsigned long long r[16];
#pragma unroll
      for (int w = 0; w < 16; ++w) r[w] = smT[w * KK1 + i];
      float rowsum = 0.f;
      for (int j = lane; j < KK1; j += 64) {
        int cnt = 0;
#pragma unroll
        for (int w = 0; w < 16; ++w) cnt += __popcll(r[w] & smT[w * KK1 + j]);
        int pj = sp[j];
        int ew = ((pj >> 8) << 2) | (pj & 3);
        int eb = (pj >> 2) & 63;
        float edge = (float)((r[ew] >> eb) & 1ull);
        float v = (j == i) ? 0.f : ((float)cnt + 2.f * edge);
        a.A1[((size_t)(b * KK1) + i) * KK1 + j] = v;
        rowsum += v;
      }
#pragma unroll
      for (int o = 32; o; o >>= 1) rowsum += __shfl_xor(rowsum, o);
      if (lane == 0) a.dis1[b * KK1 + i] = rsqrtf(rowsum + 2.0f);
    }
  }
  gbar(a.bar, phase);

  // ---- P3b: t1 = dis1*vals1*(h0[perm1]@Wd1) ----
  phase_xw32g(a.h0, a.perm1, a.vals1, a.Wd1, a.dis1, NN, KK1, 410, a.t1, tid);
  gbar(a.bar, phase);

  // ---- P4: h1 = relu(dense GCN1) ----
  phase_dense<KK1>(a.A1, a.t1, a.dis1, a.bd1, a.h1, tid, (float*)smem);
  gbar(a.bar, phase);

  // ---- P5: top-k pool 2 ----
  for (int vb = blockIdx.x; vb < BB; vb += GRID) {
    int b = vb;
    float* ss = (float*)smem;                      // KK1 floats
    float nn = 0.f;
#pragma unroll
    for (int k = 0; k < 32; ++k) nn += a.p2[k] * a.p2[k];
    float rn = sqrtf(nn);
    if (tid < KK1) {
      const float* hr = a.h1 + (size_t)(b * KK1 + tid) * 32;
      float d = 0.f;
#pragma unroll
      for (int k = 0; k < 32; ++k) d += hr[k] * a.p2[k];
      ss[tid] = tanhf(d / rn);
    }
    __syncthreads();
    if (tid < KK1) {
      float v = ss[tid];
      int rank = 0;
      for (int j = 0; j < KK1; ++j) {
        float sj = ss[j];
        rank += (sj > v || (sj == v && j < tid)) ? 1 : 0;
      }
      if (rank < KK2) {
        a.perm2[b * KK2 + rank] = tid;
        a.vals2[b * KK2 + rank] = v;
        a.inv2[b * KK1 + tid] = rank;
      } else {
        a.inv2[b * KK1 + tid] = -1;
      }
    }
  }
  gbar(a.bar, phase);

  // ---- P6a: A2 = augment(A1)[perm2,perm2] (+dis2) ----
  for (int vb = blockIdx.x; vb < BB * KK2; vb += GRID) {
    __syncthreads();
    float* gsum = (float*)smem;                    // 8 floats
    int row = vb, b = row / KK2, i = row - b * KK2;
    int g = tid >> 5, lane = tid & 31;
    int pi = a.perm2[b * KK2 + i];
    const float* Ri = a.A1 + ((size_t)(b * KK1 + pi)) * KK1;
    float part = 0.f;
    for (int j = g; j < KK2; j += 8) {
      int pj = a.perm2[b * KK2 + j];
      const float* Rj = a.A1 + ((size_t)(b * KK1 + pj)) * KK1;
      float s = 0.f;
      for (int k = lane; k < KK1; k += 32) s += Ri[k] * Rj[k];
#pragma unroll
      for (int o = 16; o; o >>= 1) s += __shfl_xor(s, o, 32);
      float v = (i == j) ? 0.f : (s + 2.0f * Ri[pj]);
      if (lane == 0) {
        a.A2[((size_t)(b * KK2) + i) * KK2 + j] = v;
        part += v;
      }
    }
    if (lane == 0) gsum[g] = part;
    __syncthreads();
    if (tid == 0) {
      float s = 0.f;
#pragma unroll
      for (int q = 0; q < 8; ++q) s += gsum[q];
      a.dis2[row] = rsqrtf(s + 2.0f);
    }
  }
  gbar(a.bar, phase);

  // ---- P6b: t2 = dis2*vals2*(h1[perm2]@Wd2) ----
  phase_xw32g(a.h1, a.perm2, a.vals2, a.Wd2, a.dis2, KK1, KK2, 84, a.t2, tid);
  gbar(a.bar, phase);

  // ---- P7: h2 = relu(dense GCN2) ----
  phase_dense<KK2>(a.A2, a.t2, a.dis2, a.bd2, a.h2, tid, (float*)smem);
  gbar(a.bar, phase);

  // ---- P8: t1 = dis1*((h1 + unpool(h2))@Wu0) ----
  phase_xw32u(a.h1, a.h2, a.inv2, a.Wu0, a.dis1, KK1, KK2, 410, a.t1, tid);
  gbar(a.bar, phase);

  // ---- P9: hu0 = relu(dense up-GCN level-1) ----
  phase_dense<KK1>(a.A1, a.t1, a.dis1, a.bu0, a.hu0, tid, (float*)smem);
  gbar(a.bar, phase);

  // ---- P10: dxw = dis0*((h0 + unpool(hu0))@Wu1) ----
  phase_xw32u(a.h0, a.hu0, a.inv1, a.Wu1, a.dis0, NN, KK1, 2048, a.dxw, tid);
  gbar(a.bar, phase);

  // ---- P11: hfin = sparse GCN (no relu) ----
  phase_spmm(a, a.dxw, a.bu1, a.hfin, false, tid);
  gbar(a.bar, phase);

  // ---- P12: batchnorm partial stats ----
  for (int vb = blockIdx.x; vb < 128; vb += GRID) {
    __syncthreads();
    float* ls = (float*)smem;                      // 256
    float* lq = ls + 256;                          // 256
    int f = tid & 31, g = tid >> 5;
    int rowBase = vb * 128;
    float s = 0.f, sq = 0.f;
    for (int r = g; r < 128; r += 8) {
      float v = a.hfin[(size_t)(rowBase + r) * 32 + f];
      s += v; sq += v * v;
    }
    ls[g * 32 + f] = s; lq[g * 32 + f] = sq;
    __syncthreads();
    if (tid < 32) {
      float S = 0.f, Q = 0.f;
#pragma unroll
      for (int i = 0; i < 8; ++i) { S += ls[i * 32 + tid]; Q += lq[i * 32 + tid]; }
      a.pacc[vb * 64 + tid] = S;
      a.pacc[vb * 64 + 32 + tid] = Q;
    }
  }
  gbar(a.bar, phase);

  // ---- P13: BN + MLP head (64 virtual blocks x 256 nodes) ----
  for (int vb = blockIdx.x; vb < 64; vb += GRID) {
    __syncthreads();
    float* sW1 = (float*)smem;        // 1024
    float* sW2 = sW1 + 1024;          // 1024
    float* sW3 = sW2 + 1024;          // 128
    float* sb1 = sW3 + 128;           // 32
    float* sb2 = sb1 + 32;            // 32
    float* sb3 = sb2 + 32;            // 32 (4 used)
    float* sscale = sb3 + 32;         // 32
    float* sshift = sscale + 32;      // 32
    for (int e = tid; e < 1024; e += TPB) { sW1[e] = a.W1[e]; sW2[e] = a.W2[e]; }
    if (tid < 128) sW3[tid] = a.W3[tid];
    if (tid < 32) { sb1[tid] = a.b1[tid]; sb2[tid] = a.b2[tid]; }
    if (tid < 4) sb3[tid] = a.b3[tid];
    if (tid < 32) {
      float S = 0.f, Q = 0.f;
      for (int q = 0; q < 128; ++q) { S += a.pacc[q * 64 + tid]; Q += a.pacc[q * 64 + 32 + tid]; }
      const float inv = 1.0f / (float)(BB * NN);
      float m = S * inv;
      float v = Q * inv - m * m;
      float sc = a.gamma[tid] * rsqrtf(v + 1e-5f);
      sscale[tid] = sc;
      sshift[tid] = a.beta[tid] - m * sc;
    }
    __syncthreads();
    int node = vb * TPB + tid;
    const float4* hr = (const float4*)(a.hfin + (size_t)node * 32);
    float hn[32];
#pragma unroll
    for (int i = 0; i < 8; ++i) {
      float4 xx = hr[i];
      hn[i * 4 + 0] = xx.x * sscale[i * 4 + 0] + sshift[i * 4 + 0];
      hn[i * 4 + 1] = xx.y * sscale[i * 4 + 1] + sshift[i * 4 + 1];
      hn[i * 4 + 2] = xx.z * sscale[i * 4 + 2] + sshift[i * 4 + 2];
      hn[i * 4 + 3] = xx.w * sscale[i * 4 + 3] + sshift[i * 4 + 3];
    }
    float r1[32];
#pragma unroll
    for (int f = 0; f < 32; ++f) r1[f] = sb1[f];
#pragma unroll
    for (int k = 0; k < 32; ++k) {
      float av = hn[k];
#pragma unroll
      for (int f = 0; f < 32; ++f) r1[f] += av * sW1[k * 32 + f];
    }
#pragma unroll
    for (int f = 0; f < 32; ++f) r1[f] = r1[f] > 0.f ? r1[f] : 0.01f * r1[f];
    float r2[32];
#pragma unroll
    for (int f = 0; f < 32; ++f) r2[f] = sb2[f];
#pragma unroll
    for (int k = 0; k < 32; ++k) {
      float av = r1[k];
#pragma unroll
      for (int f = 0; f < 32; ++f) r2[f] += av * sW2[k * 32 + f];
    }
#pragma unroll
    for (int f = 0; f < 32; ++f) r2[f] = r2[f] > 0.f ? r2[f] : 0.01f * r2[f];
    float r3[4];
#pragma unroll
    for (int c = 0; c < 4; ++c) r3[c] = sb3[c];
#pragma unroll
    for (int k = 0; k < 32; ++k) {
      float av = r2[k];
#pragma unroll
      for (int c = 0; c < 4; ++c) r3[c] += av * sW3[k * 4 + c];
    }
    float4 o;
    o.x = 1.0f / (1.0f + expf(-r3[0]));
    o.y = r3[1]; o.z = r3[2]; o.w = r3[3];
    ((float4*)a.out)[node] = o;
  }
}

extern "C" void kernel_launch(void* const* d_in, const int* in_sizes, int n_in,
                              void* d_out, int out_size, void* d_ws, size_t ws_size,
                              hipStream_t stream) {
  char* w = (char*)d_ws;
  auto alloc = [&](size_t bytes) -> void* {
    void* p = (void*)w;
    w += (bytes + 255) & ~(size_t)255;
    return p;
  };
  MegaArgs a;
  a.x    = (const float*)d_in[0];
  a.adj  = (const float*)d_in[1];
  a.Wd0  = (const float*)d_in[2];
  a.bd0  = (const float*)d_in[3];
  a.Wd1  = (const float*)d_in[4];
  a.bd1  = (const float*)d_in[5];
  a.Wd2  = (const float*)d_in[6];
  a.bd2  = (const float*)d_in[7];
  a.Wu0  = (const float*)d_in[8];
  a.bu0  = (const float*)d_in[9];
  a.Wu1  = (const float*)d_in[10];
  a.bu1  = (const float*)d_in[11];
  a.p1   = (const float*)d_in[12];
  a.p2   = (const float*)d_in[13];
  a.gamma= (const float*)d_in[14];
  a.beta = (const float*)d_in[15];
  a.W1   = (const float*)d_in[16];
  a.b1   = (const float*)d_in[17];
  a.W2   = (const float*)d_in[18];
  a.b2   = (const float*)d_in[19];
  a.W3   = (const float*)d_in[20];
  a.b3   = (const float*)d_in[21];
  a.out  = (float*)d_out;

  a.bar  = (int*)alloc(256);
  a.dis0 = (float*)alloc(BB * NN * 4);
  a.ncnt = (int*)alloc(BB * NN * 4);
  a.nbr  = (int*)alloc((size_t)BB * NN * CAP * 4);
  a.mask = (unsigned long long*)alloc((size_t)BB * NN * 16 * 8);
  a.dxw  = (float*)alloc((size_t)BB * NN * 32 * 4);
  a.h0   = (float*)alloc((size_t)BB * NN * 32 * 4);
  a.perm1= (int*)alloc(BB * KK1 * 4);
  a.vals1= (float*)alloc(BB * KK1 * 4);
  a.inv1 = (int*)alloc(BB * NN * 4);
  a.A1   = (float*)alloc((size_t)BB * KK1 * KK1 * 4);
  a.dis1 = (float*)alloc(BB * KK1 * 4);
  a.t1   = (float*)alloc((size_t)BB * KK1 * 32 * 4);
  a.h1   = (float*)alloc((size_t)BB * KK1 * 32 * 4);
  a.perm2= (int*)alloc(BB * KK2 * 4);
  a.vals2= (float*)alloc(BB * KK2 * 4);
  a.inv2 = (int*)alloc(BB * KK1 * 4);
  a.A2   = (float*)alloc((size_t)BB * KK2 * KK2 * 4);
  a.dis2 = (float*)alloc(BB * KK2 * 4);
  a.t2   = (float*)alloc((size_t)BB * KK2 * 32 * 4);
  a.h2   = (float*)alloc((size_t)BB * KK2 * 32 * 4);
  a.hu0  = (float*)alloc((size_t)BB * KK1 * 32 * 4);
  a.hfin = (float*)alloc((size_t)BB * NN * 32 * 4);
  a.pacc = (float*)alloc(128 * 64 * 4);

  hipMemsetAsync(a.bar, 0, 8, stream);
  k_mega<<<GRID, TPB, 0, stream>>>(a);
}